// Round 5
// baseline (180.002 us; speedup 1.0000x reference)
//
#include <hip/hip_runtime.h>
#include <math.h>

// Problem constants: B=8, H=8 (BH=64 heads), N=4096, D=64, M=64, 6 NS iters.
#define NSEQ 4096

// workspace offsets (in float units).
#define OFF_SUMK 0u        // (k_sums -> k_select)
#define OFF_SUMQ 262144u
#define OFF_WTH  0u        // bf16 W^T hi (k_comb -> k_final), overlaps dead SUMK
#define OFF_WTL  131072u
#define OFF_U    262144u   // (k_u -> k_nsinv), overlaps dead SUMQ
#define OFF_NC   524288u   // f32 nc (k_select -> k_u)
#define OFF_NR   786432u   // f32 nr (k_select -> k_u, k_rvp)
#define OFF_VM   1048576u  // k_nsinv -> k_comb
#define OFF_NCH  1310720u  // bf16 nc hi/lo (k_select -> k_final)
#define OFF_NCL  1441792u
#define OFF_PMAX 1572864u  // 64*nch*64 (nch<=16 -> 65536)
#define OFF_PSUM 1638400u
#define OFF_HMAX 1703936u  // 64
#define OFF_PRV  1704000u  // 64*nch*4096 (nch=16 -> 4194304 -> end 5898304 floats)

typedef unsigned short u16;
typedef short short8 __attribute__((ext_vector_type(8)));
typedef short bf4 __attribute__((ext_vector_type(4)));
typedef float f32x4 __attribute__((ext_vector_type(4)));

// ---------------- bf16 split helpers ----------------
__device__ __forceinline__ u16 f2bf(float x) {      // RNE f32->bf16 bits
    unsigned u = __float_as_uint(x);
    unsigned r = (u + 0x7FFFu + ((u >> 16) & 1u)) >> 16;
    return (u16)r;
}
__device__ __forceinline__ void splitbf(float x, u16& h, u16& l) {
    unsigned u = __float_as_uint(x);
    h = (u16)(u >> 16);                              // truncate -> exact residual
    float hf = __uint_as_float(u & 0xFFFF0000u);
    l = f2bf(x - hf);
}

// ---------------- swizzled LDS tile helpers (64x64 bf16, 128B rows) ----------------
__device__ __forceinline__ short8 ldfrag(const u16* base, int row, int k0) {
    int byte = (row << 7) + (k0 << 1);
    byte ^= (row & 7) << 4;
    return *(const short8*)((const char*)base + byte);
}
__device__ __forceinline__ void st4(u16* base, int row, int c0, ushort4 v) {
    int byte = (row << 7) + (c0 << 1);
    byte ^= (row & 7) << 4;
    *(ushort4*)((char*)base + byte) = v;
}
__device__ __forceinline__ void stb16(u16* base, int row, int c, u16 v) {
    int byte = (row << 7) + (c << 1);
    byte ^= (row & 7) << 4;
    *(u16*)((char*)base + byte) = v;
}
// V^T tile swizzle: rows are d (128B), cols n; 2-way-free b64 reads
__device__ __forceinline__ unsigned vt_byte(int d, int n) {
    unsigned byte = ((unsigned)d << 7) + ((unsigned)n << 1);
    byte ^= ((d & 7) << 4) | ((d & 8) << 3);
    return byte;
}

__device__ __forceinline__ f32x4 MFMA(short8 a, short8 b, f32x4 c) {
    return __builtin_amdgcn_mfma_f32_16x16x32_bf16(a, b, c, 0, 0, 0);
}

// stage 64x64 f32 global tile (row-major) -> hi/lo bf16 LDS, swizzled rows
__device__ __forceinline__ void stage64(const float* __restrict__ g, u16* Lh, u16* Ll,
                                        int t, float scale) {
#pragma unroll
    for (int i = 0; i < 4; i++) {
        int e = t + 256 * i;
        int row = e >> 4, c0 = (e & 15) << 2;
        float4 v = *(const float4*)(g + row * 64 + c0);
        float vv[4] = {v.x * scale, v.y * scale, v.z * scale, v.w * scale};
        ushort4 h, l;
        splitbf(vv[0], h.x, l.x); splitbf(vv[1], h.y, l.y);
        splitbf(vv[2], h.z, l.z); splitbf(vv[3], h.w, l.w);
        st4(Lh, row, c0, h); st4(Ll, row, c0, l);
    }
}

// copy 64x64 bf16 (row-major in global) -> swizzled LDS
__device__ __forceinline__ void copy64bf(u16* dst, const u16* __restrict__ src, int t) {
#pragma unroll
    for (int i = 0; i < 4; i++) {
        int e = t + 256 * i;
        int row = e >> 4, c0 = (e & 15) << 2;
        ushort4 v = *(const ushort4*)(src + row * 64 + c0);
        st4(dst, row, c0, v);
    }
}

// ---------------- f32 64x64 VALU matmul helpers (small kernels) ----------------
__device__ __forceinline__ void loadT64(float* dst, const float* __restrict__ src, int t) {
    for (int e = t; e < 1024; e += 256) {
        int m = e >> 4, k0 = (e & 15) << 2;
        float4 v = *(const float4*)(src + m * 64 + k0);
        dst[(k0 + 0) * 64 + m] = v.x;
        dst[(k0 + 1) * 64 + m] = v.y;
        dst[(k0 + 2) * 64 + m] = v.z;
        dst[(k0 + 3) * 64 + m] = v.w;
    }
}
__device__ __forceinline__ void mm64add(const float* Acm, const float* Brm,
                                        float acc[4][4], int i0, int j0) {
#pragma unroll 8
    for (int k = 0; k < 64; k++) {
        float4 a = *(const float4*)(Acm + k * 64 + i0);
        float4 b = *(const float4*)(Brm + k * 64 + j0);
        acc[0][0] += a.x * b.x; acc[0][1] += a.x * b.y; acc[0][2] += a.x * b.z; acc[0][3] += a.x * b.w;
        acc[1][0] += a.y * b.x; acc[1][1] += a.y * b.y; acc[1][2] += a.y * b.z; acc[1][3] += a.y * b.w;
        acc[2][0] += a.z * b.x; acc[2][1] += a.z * b.y; acc[2][2] += a.z * b.z; acc[2][3] += a.z * b.w;
        acc[3][0] += a.w * b.x; acc[3][1] += a.w * b.y; acc[3][2] += a.w * b.z; acc[3][3] += a.w * b.w;
    }
}
__device__ __forceinline__ void mm64(const float* Acm, const float* Brm,
                                     float acc[4][4], int i0, int j0) {
#pragma unroll
    for (int r = 0; r < 4; r++)
#pragma unroll
        for (int c = 0; c < 4; c++) acc[r][c] = 0.f;
    mm64add(Acm, Brm, acc, i0, j0);
}
__device__ __forceinline__ void writeN64(float* dst, const float acc[4][4], int i0, int j0, float s) {
#pragma unroll
    for (int r = 0; r < 4; r++) {
        float4 v;
        v.x = s * acc[r][0]; v.y = s * acc[r][1]; v.z = s * acc[r][2]; v.w = s * acc[r][3];
        *(float4*)(dst + (i0 + r) * 64 + j0) = v;
    }
}

// ---------- kernel A: row sums of Q and K ----------
__global__ __launch_bounds__(256) void k_sums(const float* __restrict__ Qg,
                                              const float* __restrict__ Kg, float* ws) {
    size_t row = (size_t)blockIdx.x * 64 + (threadIdx.x >> 2);
    int q = threadIdx.x & 3;
    const float4* qp = (const float4*)(Qg + row * 64 + q * 16);
    const float4* kp = (const float4*)(Kg + row * 64 + q * 16);
    float s1 = 0.f, s2 = 0.f;
#pragma unroll
    for (int i = 0; i < 4; i++) { float4 v = qp[i]; s1 += (v.x + v.y) + (v.z + v.w); }
#pragma unroll
    for (int i = 0; i < 4; i++) { float4 v = kp[i]; s2 += (v.x + v.y) + (v.z + v.w); }
    s1 += __shfl_xor(s1, 1); s1 += __shfl_xor(s1, 2);
    s2 += __shfl_xor(s2, 1); s2 += __shfl_xor(s2, 2);
    if (q == 0) { ws[OFF_SUMQ + row] = s1; ws[OFF_SUMK + row] = s2; }
}

// ---------- kernel B: top-64 select via MSB radix-select + gather ----------
__global__ __launch_bounds__(256) void k_select(const float* __restrict__ Qg,
                                                const float* __restrict__ Kg, float* ws) {
    int head = blockIdx.x, sel = blockIdx.y, t = threadIdx.x;
    __shared__ int hist[257];
    __shared__ int idx_s[64];
    __shared__ unsigned s_prefix;
    __shared__ int s_need, s_cnt, s_win;
    __shared__ int wred[4];
    const float* scores = ws + (sel ? OFF_SUMQ : OFF_SUMK) + (size_t)head * 4096;
    unsigned uu[16];
#pragma unroll
    for (int i = 0; i < 16; i++) {
        unsigned u = __float_as_uint(scores[t + 256 * i]);
        uu[i] = (u & 0x80000000u) ? ~u : (u | 0x80000000u);
    }
    if (t == 0) { s_prefix = 0u; s_need = 64; }
    __syncthreads();
#pragma unroll
    for (int p = 0; p < 4; p++) {
        hist[t] = 0;
        if (t == 0) hist[256] = 0;
        __syncthreads();
        unsigned pref = s_prefix;
        int sh = 32 - 8 * p;
        int dsh = 24 - 8 * p;
#pragma unroll
        for (int i = 0; i < 16; i++) {
            bool active = (p == 0) || ((uu[i] >> sh) == (pref >> sh));
            if (active) atomicAdd(&hist[(uu[i] >> dsh) & 255], 1);
        }
        __syncthreads();
        for (int s = 1; s < 256; s <<= 1) {
            int v = (t + s < 256) ? hist[t + s] : 0;
            __syncthreads();
            hist[t] += v;
            __syncthreads();
        }
        int need = s_need;
        __syncthreads();
        if (hist[t] >= need && (t == 255 || hist[t + 1] < need)) {
            s_need = need - ((t == 255) ? 0 : hist[t + 1]);
            s_prefix = pref | ((unsigned)t << dsh);
        }
        __syncthreads();
    }
    unsigned thr = s_prefix;
    int needEq = s_need;
    if (t == 0) s_cnt = 0;
    __syncthreads();
    unsigned eqm = 0;
#pragma unroll
    for (int i = 0; i < 16; i++) {
        if (uu[i] > thr) { int pos = atomicAdd(&s_cnt, 1); idx_s[pos] = t + 256 * i; }
        else if (uu[i] == thr) eqm |= (1u << i);
    }
    __syncthreads();
    int base = 64 - needEq;
    int lane = t & 63, wid = t >> 6;
    for (int r = 0; r < needEq; r++) {
        int mymin = 0x7FFFFFFF;
#pragma unroll
        for (int i = 0; i < 16; i++)
            if ((eqm >> i) & 1) mymin = min(mymin, t + 256 * i);
#pragma unroll
        for (int s = 1; s < 64; s <<= 1) mymin = min(mymin, __shfl_xor(mymin, s));
        if (lane == 0) wred[wid] = mymin;
        __syncthreads();
        if (t == 0) {
            int wv = min(min(wred[0], wred[1]), min(wred[2], wred[3]));
            s_win = wv;
            idx_s[base + r] = wv;
        }
        __syncthreads();
        int wv = s_win;
        if ((wv & 255) == t) eqm &= ~(1u << (wv >> 8));
        __syncthreads();
    }
    // gather selected rows
    const float* src = sel ? Qg : Kg;
    float* dst = ws + (sel ? OFF_NR : OFF_NC) + (size_t)head * 4096;
    u16* dh = (u16*)(ws + OFF_NCH) + (size_t)head * 4096;
    u16* dl = (u16*)(ws + OFF_NCL) + (size_t)head * 4096;
    float scl = sel ? 0.125f : 1.0f;
    for (int e = t; e < 4096; e += 256) {
        int m = e >> 6, d = e & 63;
        float v = src[((size_t)head * NSEQ + (size_t)idx_s[m]) * 64 + d] * scl;
        dst[e] = v;
        if (!sel) { u16 h, l; splitbf(v, h, l); dh[e] = h; dl[e] = l; }
    }
}

// ---------- kernel C: u = softmax(nr @ nc^T) + per-head max colsum ----------
__global__ __launch_bounds__(256) void k_u(float* ws) {
    int head = blockIdx.x, t = threadIdx.x;
    __shared__ __align__(16) float A_s[4096];
    __shared__ __align__(16) float B_s[4096];
    __shared__ float colpart[1024];
    loadT64(A_s, ws + OFF_NR + (size_t)head * 4096, t);
    loadT64(B_s, ws + OFF_NC + (size_t)head * 4096, t);
    __syncthreads();
    int ti = t >> 4, tj = t & 15, i0 = ti << 2, j0 = tj << 2;
    float acc[4][4];
    mm64(A_s, B_s, acc, i0, j0);
#pragma unroll
    for (int r = 0; r < 4; r++) {
        float m0 = fmaxf(fmaxf(acc[r][0], acc[r][1]), fmaxf(acc[r][2], acc[r][3]));
        m0 = fmaxf(m0, __shfl_xor(m0, 1)); m0 = fmaxf(m0, __shfl_xor(m0, 2));
        m0 = fmaxf(m0, __shfl_xor(m0, 4)); m0 = fmaxf(m0, __shfl_xor(m0, 8));
        float s = 0.f;
#pragma unroll
        for (int c = 0; c < 4; c++) { acc[r][c] = __expf(acc[r][c] - m0); s += acc[r][c]; }
        s += __shfl_xor(s, 1); s += __shfl_xor(s, 2);
        s += __shfl_xor(s, 4); s += __shfl_xor(s, 8);
#pragma unroll
        for (int c = 0; c < 4; c++) acc[r][c] = acc[r][c] / s;
    }
    float* u = ws + OFF_U + (size_t)head * 4096;
#pragma unroll
    for (int r = 0; r < 4; r++) {
        float4 v; v.x = acc[r][0]; v.y = acc[r][1]; v.z = acc[r][2]; v.w = acc[r][3];
        *(float4*)(u + (i0 + r) * 64 + j0) = v;
    }
#pragma unroll
    for (int c = 0; c < 4; c++)
        colpart[ti * 64 + j0 + c] = acc[0][c] + acc[1][c] + acc[2][c] + acc[3][c];
    __syncthreads();
    if (t < 64) {
        float cs = 0.f;
#pragma unroll
        for (int g = 0; g < 16; g++) cs += colpart[g * 64 + t];
        float v = cs;
#pragma unroll
        for (int s = 1; s < 64; s <<= 1) v = fmaxf(v, __shfl_xor(v, s));
        if (t == 0) ws[OFF_HMAX + head] = v;
    }
}

// ---------- kernel E: Newton-Schulz inverse via MFMA split-bf16 ----------
__global__ __launch_bounds__(256) void k_nsinv(float* ws) {
    int head = blockIdx.x, t = threadIdx.x;
    __shared__ __align__(16) u16 KmH[4096], KmL[4096];
    __shared__ __align__(16) u16 VmNH[4096], VmNL[4096];
    __shared__ __align__(16) u16 VmTH[4096], VmTL[4096];
    __shared__ __align__(16) u16 KVH[4096], KVL[4096];
    __shared__ __align__(16) u16 BtH[4096], BtL[4096];
    __shared__ __align__(16) float Vmf[4096];

    int w = t >> 6, lane = t & 63, lrow = lane & 15, lk = (lane >> 4) << 3;
    int mrow0 = 16 * w + ((lane >> 4) << 2);

    float g = ws[OFF_HMAX + lane];
#pragma unroll
    for (int s = 1; s < 64; s <<= 1) g = fmaxf(g, __shfl_xor(g, s));
    float ginv = 1.0f / g;

    const float* u = ws + OFF_U + (size_t)head * 4096;
#pragma unroll
    for (int i = 0; i < 4; i++) {
        int e = t + 256 * i;
        int row = e >> 4, c0 = (e & 15) << 2;
        float4 v = *(const float4*)(u + row * 64 + c0);
        float vv[4] = {v.x, v.y, v.z, v.w};
        ushort4 h4, l4;
        splitbf(vv[0], h4.x, l4.x); splitbf(vv[1], h4.y, l4.y);
        splitbf(vv[2], h4.z, l4.z); splitbf(vv[3], h4.w, l4.w);
        st4(KmH, row, c0, h4); st4(KmL, row, c0, l4);
        float sv[4] = {vv[0] * ginv, vv[1] * ginv, vv[2] * ginv, vv[3] * ginv};
        splitbf(sv[0], h4.x, l4.x); splitbf(sv[1], h4.y, l4.y);
        splitbf(sv[2], h4.z, l4.z); splitbf(sv[3], h4.w, l4.w);
        st4(VmTH, row, c0, h4); st4(VmTL, row, c0, l4);
#pragma unroll
        for (int k = 0; k < 4; k++) {
            u16 h, l; splitbf(sv[k], h, l);
            stb16(VmNH, c0 + k, row, h); stb16(VmNL, c0 + k, row, l);
            Vmf[(c0 + k) * 64 + row] = sv[k];
        }
    }
    __syncthreads();

    f32x4 cv[4];
    // helper lambda-free: C[m][n] = sum_k A[m][k]*B[n][k]
    for (int it = 0; it < 6; it++) {
        {
            short8 a0h = ldfrag(KmH, 16 * w + lrow, lk);
            short8 a0l = ldfrag(KmL, 16 * w + lrow, lk);
            short8 a1h = ldfrag(KmH, 16 * w + lrow, 32 + lk);
            short8 a1l = ldfrag(KmL, 16 * w + lrow, 32 + lk);
#pragma unroll
            for (int nt = 0; nt < 4; nt++) {
                f32x4 acc = (f32x4){0.f, 0.f, 0.f, 0.f};
                short8 bh = ldfrag(VmTH, 16 * nt + lrow, lk);
                short8 bl = ldfrag(VmTL, 16 * nt + lrow, lk);
                acc = MFMA(a0h, bh, acc); acc = MFMA(a0l, bh, acc); acc = MFMA(a0h, bl, acc);
                bh = ldfrag(VmTH, 16 * nt + lrow, 32 + lk);
                bl = ldfrag(VmTL, 16 * nt + lrow, 32 + lk);
                acc = MFMA(a1h, bh, acc); acc = MFMA(a1l, bh, acc); acc = MFMA(a1h, bl, acc);
                cv[nt] = acc;
            }
        }
#pragma unroll
        for (int nt = 0; nt < 4; nt++)
#pragma unroll
            for (int j = 0; j < 4; j++) {
                int m = mrow0 + j, n = 16 * nt + lrow;
                float v = cv[nt][j];
                u16 h, l; splitbf(v, h, l);
                stb16(KVH, m, n, h); stb16(KVL, m, n, l);
                float b = ((m == n) ? 7.f : 0.f) - v;
                splitbf(b, h, l);
                stb16(BtH, n, m, h); stb16(BtL, n, m, l);
            }
        __syncthreads();
        {
            short8 a0h = ldfrag(KVH, 16 * w + lrow, lk);
            short8 a0l = ldfrag(KVL, 16 * w + lrow, lk);
            short8 a1h = ldfrag(KVH, 16 * w + lrow, 32 + lk);
            short8 a1l = ldfrag(KVL, 16 * w + lrow, 32 + lk);
#pragma unroll
            for (int nt = 0; nt < 4; nt++) {
                f32x4 acc = (f32x4){0.f, 0.f, 0.f, 0.f};
                short8 bh = ldfrag(BtH, 16 * nt + lrow, lk);
                short8 bl = ldfrag(BtL, 16 * nt + lrow, lk);
                acc = MFMA(a0h, bh, acc); acc = MFMA(a0l, bh, acc); acc = MFMA(a0h, bl, acc);
                bh = ldfrag(BtH, 16 * nt + lrow, 32 + lk);
                bl = ldfrag(BtL, 16 * nt + lrow, 32 + lk);
                acc = MFMA(a1h, bh, acc); acc = MFMA(a1l, bh, acc); acc = MFMA(a1h, bl, acc);
                cv[nt] = acc;
            }
        }
        __syncthreads();
#pragma unroll
        for (int nt = 0; nt < 4; nt++)
#pragma unroll
            for (int j = 0; j < 4; j++) {
                int m = mrow0 + j, n = 16 * nt + lrow;
                float b = ((m == n) ? 15.f : 0.f) - cv[nt][j];
                u16 h, l; splitbf(b, h, l);
                stb16(BtH, n, m, h); stb16(BtL, n, m, l);
            }
        __syncthreads();
        {
            short8 a0h = ldfrag(KVH, 16 * w + lrow, lk);
            short8 a0l = ldfrag(KVL, 16 * w + lrow, lk);
            short8 a1h = ldfrag(KVH, 16 * w + lrow, 32 + lk);
            short8 a1l = ldfrag(KVL, 16 * w + lrow, 32 + lk);
#pragma unroll
            for (int nt = 0; nt < 4; nt++) {
                f32x4 acc = (f32x4){0.f, 0.f, 0.f, 0.f};
                short8 bh = ldfrag(BtH, 16 * nt + lrow, lk);
                short8 bl = ldfrag(BtL, 16 * nt + lrow, lk);
                acc = MFMA(a0h, bh, acc); acc = MFMA(a0l, bh, acc); acc = MFMA(a0h, bl, acc);
                bh = ldfrag(BtH, 16 * nt + lrow, 32 + lk);
                bl = ldfrag(BtL, 16 * nt + lrow, 32 + lk);
                acc = MFMA(a1h, bh, acc); acc = MFMA(a1l, bh, acc); acc = MFMA(a1h, bl, acc);
                cv[nt] = acc;
            }
        }
        __syncthreads();
#pragma unroll
        for (int nt = 0; nt < 4; nt++)
#pragma unroll
            for (int j = 0; j < 4; j++) {
                int m = mrow0 + j, n = 16 * nt + lrow;
                float b = ((m == n) ? 13.f : 0.f) - cv[nt][j];
                u16 h, l; splitbf(b, h, l);
                stb16(BtH, n, m, h); stb16(BtL, n, m, l);
            }
        __syncthreads();
        {
            short8 a0h = ldfrag(VmNH, 16 * w + lrow, lk);
            short8 a0l = ldfrag(VmNL, 16 * w + lrow, lk);
            short8 a1h = ldfrag(VmNH, 16 * w + lrow, 32 + lk);
            short8 a1l = ldfrag(VmNL, 16 * w + lrow, 32 + lk);
#pragma unroll
            for (int nt = 0; nt < 4; nt++) {
                f32x4 acc = (f32x4){0.f, 0.f, 0.f, 0.f};
                short8 bh = ldfrag(BtH, 16 * nt + lrow, lk);
                short8 bl = ldfrag(BtL, 16 * nt + lrow, lk);
                acc = MFMA(a0h, bh, acc); acc = MFMA(a0l, bh, acc); acc = MFMA(a0h, bl, acc);
                bh = ldfrag(BtH, 16 * nt + lrow, 32 + lk);
                bl = ldfrag(BtL, 16 * nt + lrow, 32 + lk);
                acc = MFMA(a1h, bh, acc); acc = MFMA(a1l, bh, acc); acc = MFMA(a1h, bl, acc);
                cv[nt] = acc;
            }
        }
        __syncthreads();
#pragma unroll
        for (int nt = 0; nt < 4; nt++)
#pragma unroll
            for (int j = 0; j < 4; j++) {
                int m = mrow0 + j, n = 16 * nt + lrow;
                float v = 0.25f * cv[nt][j];
                u16 h, l; splitbf(v, h, l);
                stb16(VmNH, m, n, h); stb16(VmNL, m, n, l);
                stb16(VmTH, n, m, h); stb16(VmTL, n, m, l);
                Vmf[m * 64 + n] = v;
            }
        __syncthreads();
    }

    float* vm = ws + OFF_VM + (size_t)head * 4096;
#pragma unroll
    for (int i = 0; i < 4; i++) {
        int e = t + 256 * i;
        int row = e >> 4, c0 = (e & 15) << 2;
        *(float4*)(vm + row * 64 + c0) = *(const float4*)(Vmf + row * 64 + c0);
    }
}

// ---------- kernel F: flash softmax(nr@K^T)@V partials — swapped-QK, in-reg P ----------
__global__ __launch_bounds__(256) void k_rvp(const float* __restrict__ Kg,
                                             const float* __restrict__ Vg, float* ws) {
    int head = blockIdx.x, ch = blockIdx.y, t = threadIdx.x;
    int nch = gridDim.y;
    int nsub = (NSEQ / 64) / nch;            // subtiles of 64 rows per chunk
    __shared__ __align__(16) u16 Kh[4096], Kl[4096];
    __shared__ __align__(16) u16 Vth[4096], Vtl[4096];   // V^T: rows d, cols n
    int w = t >> 6, lane = t & 63, lrow = lane & 15, g = lane >> 4;
    int lk = g << 3;
    int mrow0 = 16 * w + (g << 2);

    // nr B-fragments direct from global f32 (row = 16w + lrow, cols lk.. / 32+lk..)
    short8 nh0, nl0, nh1, nl1;
    {
        const float* nr = ws + OFF_NR + (size_t)head * 4096 + (size_t)(16 * w + lrow) * 64;
        float a[8], b[8];
        *(float4*)(a + 0) = *(const float4*)(nr + lk);
        *(float4*)(a + 4) = *(const float4*)(nr + lk + 4);
        *(float4*)(b + 0) = *(const float4*)(nr + 32 + lk);
        *(float4*)(b + 4) = *(const float4*)(nr + 32 + lk + 4);
#pragma unroll
        for (int i = 0; i < 8; i++) {
            u16 h, l;
            splitbf(a[i], h, l); nh0[i] = (short)h; nl0[i] = (short)l;
            splitbf(b[i], h, l); nh1[i] = (short)h; nl1[i] = (short)l;
        }
    }

    f32x4 rv[4];
#pragma unroll
    for (int dt = 0; dt < 4; dt++) rv[dt] = (f32x4){0.f, 0.f, 0.f, 0.f};
    float mrow = -INFINITY, srow = 0.f;      // stats for P-row m = 16w + lrow

    int rows = NSEQ / nch;
    const float* Kb = Kg + ((size_t)head * NSEQ + (size_t)ch * rows) * 64;
    const float* Vb = Vg + ((size_t)head * NSEQ + (size_t)ch * rows) * 64;
    int vd = lane;                            // this lane's d column for V staging
    int nb4 = (t >> 6) << 2;                  // V staging n-offset per wave

    for (int s8 = 0; s8 < nsub; s8++) {
        __syncthreads();                      // prior reads of Kh/Vt complete
        stage64(Kb + s8 * 4096, Kh, Kl, t, 1.0f);
        // V d-major staging: coalesced dword loads, ushort4 transposed stores
        const float* Vs = Vb + s8 * 4096;
#pragma unroll
        for (int i = 0; i < 4; i++) {
            int n0 = nb4 + 16 * i;
            float x0 = Vs[(n0 + 0) * 64 + vd];
            float x1 = Vs[(n0 + 1) * 64 + vd];
            float x2 = Vs[(n0 + 2) * 64 + vd];
            float x3 = Vs[(n0 + 3) * 64 + vd];
            ushort4 h4, l4;
            splitbf(x0, h4.x, l4.x); splitbf(x1, h4.y, l4.y);
            splitbf(x2, h4.z, l4.z); splitbf(x3, h4.w, l4.w);
            *(ushort4*)((char*)Vth + vt_byte(vd, n0)) = h4;
            *(ushort4*)((char*)Vtl + vt_byte(vd, n0)) = l4;
        }
        __syncthreads();

        // swapped QK^T: cv[nt][j] = S[m = 16w+lrow][n = 16nt + 4g + j]
        f32x4 cv[4];
#pragma unroll
        for (int nt = 0; nt < 4; nt++) {
            f32x4 acc = (f32x4){0.f, 0.f, 0.f, 0.f};
            short8 ah = ldfrag(Kh, 16 * nt + lrow, lk);
            short8 al = ldfrag(Kl, 16 * nt + lrow, lk);
            acc = MFMA(ah, nh0, acc); acc = MFMA(al, nh0, acc); acc = MFMA(ah, nl0, acc);
            ah = ldfrag(Kh, 16 * nt + lrow, 32 + lk);
            al = ldfrag(Kl, 16 * nt + lrow, 32 + lk);
            acc = MFMA(ah, nh1, acc); acc = MFMA(al, nh1, acc); acc = MFMA(ah, nl1, acc);
            cv[nt] = acc;
        }
        // row softmax: reduce over 16 regs + g-groups (lanes ^16, ^32)
        float m0 = cv[0][0];
#pragma unroll
        for (int nt = 0; nt < 4; nt++)
#pragma unroll
            for (int j = 0; j < 4; j++) m0 = fmaxf(m0, cv[nt][j]);
        m0 = fmaxf(m0, __shfl_xor(m0, 16));
        m0 = fmaxf(m0, __shfl_xor(m0, 32));
        float mnew = fmaxf(mrow, m0);
        float sc = __expf(mrow - mnew);
        float ps = 0.f;
#pragma unroll
        for (int nt = 0; nt < 4; nt++)
#pragma unroll
            for (int j = 0; j < 4; j++) {
                float p = __expf(cv[nt][j] - mnew);
                cv[nt][j] = p; ps += p;
            }
        ps += __shfl_xor(ps, 16);
        ps += __shfl_xor(ps, 32);
        srow = srow * sc + ps;
        mrow = mnew;
        // rescale rv rows (rv rows are m = mrow0+j; stats live on lane class 4g+j)
        float scl[4];
#pragma unroll
        for (int j = 0; j < 4; j++) scl[j] = __shfl(sc, (g << 2) + j);
#pragma unroll
        for (int dt = 0; dt < 4; dt++)
#pragma unroll
            for (int j = 0; j < 4; j++) rv[dt][j] *= scl[j];
        // pack P into A-fragments: slot 8g+i <-> n = 32h2 + 16(i>>2) + 4g + (i&3)
        short8 pah[2], pal[2];
#pragma unroll
        for (int h2 = 0; h2 < 2; h2++)
#pragma unroll
            for (int i = 0; i < 8; i++) {
                u16 hh, ll;
                splitbf(cv[2 * h2 + (i >> 2)][i & 3], hh, ll);
                pah[h2][i] = (short)hh; pal[h2][i] = (short)ll;
            }
        // PV: B-frag = V^T[d = 16dt+lrow][slots], two b64 reads per frag
#pragma unroll
        for (int dt = 0; dt < 4; dt++) {
            int drow = 16 * dt + lrow;
#pragma unroll
            for (int h2 = 0; h2 < 2; h2++) {
                bf4 xh0 = *(const bf4*)((const char*)Vth + vt_byte(drow, 32 * h2 + 4 * g));
                bf4 xh1 = *(const bf4*)((const char*)Vth + vt_byte(drow, 32 * h2 + 16 + 4 * g));
                bf4 xl0 = *(const bf4*)((const char*)Vtl + vt_byte(drow, 32 * h2 + 4 * g));
                bf4 xl1 = *(const bf4*)((const char*)Vtl + vt_byte(drow, 32 * h2 + 16 + 4 * g));
                short8 bh = __builtin_shufflevector(xh0, xh1, 0, 1, 2, 3, 4, 5, 6, 7);
                short8 bl = __builtin_shufflevector(xl0, xl1, 0, 1, 2, 3, 4, 5, 6, 7);
                rv[dt] = MFMA(pah[h2], bh, rv[dt]);
                rv[dt] = MFMA(pal[h2], bh, rv[dt]);
                rv[dt] = MFMA(pah[h2], bl, rv[dt]);
            }
        }
    }
    size_t pb = (size_t)(head * nch + ch) * 64;
    if (lane < 16) {
        ws[OFF_PMAX + pb + 16 * w + lane] = mrow;
        ws[OFF_PSUM + pb + 16 * w + lane] = srow;
    }
#pragma unroll
    for (int dt = 0; dt < 4; dt++)
#pragma unroll
        for (int j = 0; j < 4; j++)
            ws[OFF_PRV + (pb + mrow0 + j) * 64 + 16 * dt + lrow] = rv[dt][j];
}

// ---------- kernel G: combine partials -> RV; W = k2inv @ RV; write W^T bf16 ----------
__global__ __launch_bounds__(256) void k_comb(float* ws, int nch) {
    int head = blockIdx.x, t = threadIdx.x;
    __shared__ __align__(16) float A_s[4096];
    __shared__ __align__(16) float B_s[4096];
    loadT64(A_s, ws + OFF_VM + (size_t)head * 4096, t);
    int ti = t >> 4, tj = t & 15, i0 = ti << 2, j0 = tj << 2;
    const float* pm = ws + OFF_PMAX + (size_t)head * nch * 64;
    const float* psv = ws + OFF_PSUM + (size_t)head * nch * 64;
    const float* prv = ws + OFF_PRV + (size_t)head * nch * 4096;
    float gm[4] = {-INFINITY, -INFINITY, -INFINITY, -INFINITY};
    for (int c8 = 0; c8 < nch; c8++)
#pragma unroll
        for (int r = 0; r < 4; r++) gm[r] = fmaxf(gm[r], pm[c8 * 64 + i0 + r]);
    float stot[4] = {0.f, 0.f, 0.f, 0.f};
    float racc[4][4];
#pragma unroll
    for (int r = 0; r < 4; r++)
#pragma unroll
        for (int c = 0; c < 4; c++) racc[r][c] = 0.f;
    for (int c8 = 0; c8 < nch; c8++) {
#pragma unroll
        for (int r = 0; r < 4; r++) {
            float w = __expf(pm[c8 * 64 + i0 + r] - gm[r]);
            stot[r] += w * psv[c8 * 64 + i0 + r];
            float4 v = *(const float4*)(prv + (size_t)(c8 * 64 + i0 + r) * 64 + j0);
            racc[r][0] += w * v.x; racc[r][1] += w * v.y;
            racc[r][2] += w * v.z; racc[r][3] += w * v.w;
        }
    }
#pragma unroll
    for (int r = 0; r < 4; r++)
#pragma unroll
        for (int c = 0; c < 4; c++) racc[r][c] /= stot[r];
    writeN64(B_s, racc, i0, j0, 1.f);
    __syncthreads();
    float acc[4][4];
    mm64(A_s, B_s, acc, i0, j0);
    u16* wth = (u16*)(ws + OFF_WTH) + (size_t)head * 4096;
    u16* wtl = (u16*)(ws + OFF_WTL) + (size_t)head * 4096;
#pragma unroll
    for (int r = 0; r < 4; r++)
#pragma unroll
        for (int c = 0; c < 4; c++) {
            u16 h, l; splitbf(acc[r][c], h, l);
            wth[(j0 + c) * 64 + (i0 + r)] = h;   // W^T[d][n]
            wtl[(j0 + c) * 64 + (i0 + r)] = l;
        }
}

// ---------- kernel H: X = softmax(Q@nc^T/8) @ W — MFMA split-bf16 ----------
__global__ __launch_bounds__(256) void k_final(const float* __restrict__ Qg, float* ws,
                                               float* __restrict__ out) {
    int tile = blockIdx.x, head = blockIdx.y, t = threadIdx.x;
    __shared__ __align__(16) u16 Ah[4096], Al[4096];   // Q then P
    __shared__ __align__(16) u16 Bh[4096], Bl[4096];   // nc then W^T
    __shared__ __align__(16) float C[64 * 68];
    const float* Qt = Qg + ((size_t)head * NSEQ + (size_t)tile * 64) * 64;
    stage64(Qt, Ah, Al, t, 0.125f);
    copy64bf(Bh, (const u16*)(ws + OFF_NCH) + (size_t)head * 4096, t);
    copy64bf(Bl, (const u16*)(ws + OFF_NCL) + (size_t)head * 4096, t);
    __syncthreads();
    int w = t >> 6, lane = t & 63, lrow = lane & 15, lk = (lane >> 4) << 3;
    int mrow0 = 16 * w + ((lane >> 4) << 2);
    short8 a0h = ldfrag(Ah, 16 * w + lrow, lk);
    short8 a0l = ldfrag(Al, 16 * w + lrow, lk);
    short8 a1h = ldfrag(Ah, 16 * w + lrow, 32 + lk);
    short8 a1l = ldfrag(Al, 16 * w + lrow, 32 + lk);
    f32x4 sa[4];
#pragma unroll
    for (int nt = 0; nt < 4; nt++) {
        f32x4 acc = (f32x4){0.f, 0.f, 0.f, 0.f};
        short8 bh = ldfrag(Bh, 16 * nt + lrow, lk);
        short8 bl = ldfrag(Bl, 16 * nt + lrow, lk);
        acc = MFMA(a0h, bh, acc); acc = MFMA(a0l, bh, acc); acc = MFMA(a0h, bl, acc);
        bh = ldfrag(Bh, 16 * nt + lrow, 32 + lk);
        bl = ldfrag(Bl, 16 * nt + lrow, 32 + lk);
        acc = MFMA(a1h, bh, acc); acc = MFMA(a1l, bh, acc); acc = MFMA(a1h, bl, acc);
        sa[nt] = acc;
    }
#pragma unroll
    for (int j = 0; j < 4; j++) {
        float m0 = fmaxf(fmaxf(sa[0][j], sa[1][j]), fmaxf(sa[2][j], sa[3][j]));
        m0 = fmaxf(m0, __shfl_xor(m0, 1)); m0 = fmaxf(m0, __shfl_xor(m0, 2));
        m0 = fmaxf(m0, __shfl_xor(m0, 4)); m0 = fmaxf(m0, __shfl_xor(m0, 8));
        float ps = 0.f;
#pragma unroll
        for (int nt = 0; nt < 4; nt++) {
            float p = __expf(sa[nt][j] - m0);
            sa[nt][j] = p; ps += p;
        }
        ps += __shfl_xor(ps, 1); ps += __shfl_xor(ps, 2);
        ps += __shfl_xor(ps, 4); ps += __shfl_xor(ps, 8);
        float inv = 1.f / ps;
#pragma unroll
        for (int nt = 0; nt < 4; nt++) sa[nt][j] *= inv;
    }
    __syncthreads();                           // done reading Q/nc from LDS
#pragma unroll
    for (int nt = 0; nt < 4; nt++)
#pragma unroll
        for (int j = 0; j < 4; j++) {
            u16 h, l; splitbf(sa[nt][j], h, l);
            stb16(Ah, mrow0 + j, 16 * nt + lrow, h);
            stb16(Al, mrow0 + j, 16 * nt + lrow, l);
        }
    copy64bf(Bh, (const u16*)(ws + OFF_WTH) + (size_t)head * 4096, t);
    copy64bf(Bl, (const u16*)(ws + OFF_WTL) + (size_t)head * 4096, t);
    __syncthreads();
    short8 p0h = ldfrag(Ah, 16 * w + lrow, lk);
    short8 p0l = ldfrag(Al, 16 * w + lrow, lk);
    short8 p1h = ldfrag(Ah, 16 * w + lrow, 32 + lk);
    short8 p1l = ldfrag(Al, 16 * w + lrow, 32 + lk);
#pragma unroll
    for (int dt = 0; dt < 4; dt++) {
        f32x4 x = (f32x4){0.f, 0.f, 0.f, 0.f};
        short8 bh = ldfrag(Bh, 16 * dt + lrow, lk);
        short8 bl = ldfrag(Bl, 16 * dt + lrow, lk);
        x = MFMA(p0h, bh, x); x = MFMA(p0l, bh, x); x = MFMA(p0h, bl, x);
        bh = ldfrag(Bh, 16 * dt + lrow, 32 + lk);
        bl = ldfrag(Bl, 16 * dt + lrow, 32 + lk);
        x = MFMA(p1h, bh, x); x = MFMA(p1l, bh, x); x = MFMA(p1h, bl, x);
#pragma unroll
        for (int j = 0; j < 4; j++) C[(mrow0 + j) * 68 + 16 * dt + lrow] = x[j];
    }
    __syncthreads();
    float* op = out + ((size_t)head * NSEQ + (size_t)tile * 64) * 64;
#pragma unroll
    for (int i = 0; i < 4; i++) {
        int e = t + 256 * i;
        int row = e >> 4, c0 = (e & 15) << 2;
        *(float4*)(op + row * 64 + c0) = *(const float4*)(C + row * 68 + c0);
    }
}

// ---------- launcher ----------
extern "C" void kernel_launch(void* const* d_in, const int* in_sizes, int n_in,
                              void* d_out, int out_size, void* d_ws, size_t ws_size,
                              hipStream_t stream) {
    const float* Q = (const float*)d_in[0];
    const float* K = (const float*)d_in[1];
    const float* V = (const float*)d_in[2];
    float* ws = (float*)d_ws;
    float* out = (float*)d_out;

    size_t need16 = ((size_t)OFF_PRV + 64ull * 16ull * 4096ull) * sizeof(float);
    int nch = (ws_size >= need16) ? 16 : 8;

    k_sums<<<4096, 256, 0, stream>>>(Q, K, ws);
    k_select<<<dim3(64, 2), 256, 0, stream>>>(Q, K, ws);
    k_u<<<64, 256, 0, stream>>>(ws);
    k_rvp<<<dim3(64, nch), 256, 0, stream>>>(K, V, ws);
    k_nsinv<<<64, 256, 0, stream>>>(ws);
    k_comb<<<64, 256, 0, stream>>>(ws, nch);
    k_final<<<dim3(64, 64), 256, 0, stream>>>(Q, ws, out);
}

// Round 6
// 144.748 us; speedup vs baseline: 1.2436x; 1.2436x over previous
//
#include <hip/hip_runtime.h>
#include <math.h>

// Problem constants: B=8, H=8 (BH=64 heads), N=4096, D=64, M=64, 6 NS iters.
#define NSEQ 4096
#define NCH  8

// workspace offsets (in float units).
#define OFF_SUMK 0u        // (k_sums -> k_select)
#define OFF_SUMQ 262144u
#define OFF_WTH  0u        // bf16 W^T hi (k_comb -> k_final), overlaps dead SUMK
#define OFF_WTL  131072u
#define OFF_U    262144u   // (k_u -> k_nsinv), overlaps dead SUMQ
#define OFF_NC   524288u   // f32 nc (k_select -> k_u)
#define OFF_NR   786432u   // f32 nr (k_select -> k_u, k_rvp)
#define OFF_VM   1048576u  // k_nsinv -> k_comb
#define OFF_NCH  1310720u  // bf16 nc hi/lo (k_select -> k_final)
#define OFF_NCL  1441792u
#define OFF_PMAX 1572864u
#define OFF_PSUM 1638400u
#define OFF_HMAX 1703936u  // 64
#define OFF_PRV  1704000u  // 64*NCH*4096

typedef unsigned short u16;
typedef short short8 __attribute__((ext_vector_type(8)));
typedef short bf4 __attribute__((ext_vector_type(4)));
typedef float f32x4 __attribute__((ext_vector_type(4)));

// ---------------- bf16 split helpers ----------------
__device__ __forceinline__ u16 f2bf(float x) {      // RNE f32->bf16 bits
    unsigned u = __float_as_uint(x);
    unsigned r = (u + 0x7FFFu + ((u >> 16) & 1u)) >> 16;
    return (u16)r;
}
__device__ __forceinline__ void splitbf(float x, u16& h, u16& l) {
    unsigned u = __float_as_uint(x);
    h = (u16)(u >> 16);                              // truncate -> exact residual
    float hf = __uint_as_float(u & 0xFFFF0000u);
    l = f2bf(x - hf);
}

// ---------------- swizzled LDS tile helpers (64x64 bf16, 128B rows) ----------------
__device__ __forceinline__ short8 ldfrag(const u16* base, int row, int k0) {
    int byte = (row << 7) + (k0 << 1);
    byte ^= (row & 7) << 4;
    return *(const short8*)((const char*)base + byte);
}
__device__ __forceinline__ void st4(u16* base, int row, int c0, ushort4 v) {
    int byte = (row << 7) + (c0 << 1);
    byte ^= (row & 7) << 4;
    *(ushort4*)((char*)base + byte) = v;
}
__device__ __forceinline__ void stb16(u16* base, int row, int c, u16 v) {
    int byte = (row << 7) + (c << 1);
    byte ^= (row & 7) << 4;
    *(u16*)((char*)base + byte) = v;
}
// V^T tile swizzle: rows are d (128B), cols n. Bijective: XOR bits 3..6 by d&15.
__device__ __forceinline__ unsigned vt_byte(int d, int n) {
    unsigned byte = ((unsigned)d << 7) + ((unsigned)n << 1);
    byte ^= (unsigned)(d & 15) << 3;
    return byte;
}

__device__ __forceinline__ f32x4 MFMA(short8 a, short8 b, f32x4 c) {
    return __builtin_amdgcn_mfma_f32_16x16x32_bf16(a, b, c, 0, 0, 0);
}

// stage 64x64 f32 global tile (row-major) -> hi/lo bf16 LDS, swizzled rows
__device__ __forceinline__ void stage64(const float* __restrict__ g, u16* Lh, u16* Ll,
                                        int t, float scale) {
#pragma unroll
    for (int i = 0; i < 4; i++) {
        int e = t + 256 * i;
        int row = e >> 4, c0 = (e & 15) << 2;
        float4 v = *(const float4*)(g + row * 64 + c0);
        float vv[4] = {v.x * scale, v.y * scale, v.z * scale, v.w * scale};
        ushort4 h, l;
        splitbf(vv[0], h.x, l.x); splitbf(vv[1], h.y, l.y);
        splitbf(vv[2], h.z, l.z); splitbf(vv[3], h.w, l.w);
        st4(Lh, row, c0, h); st4(Ll, row, c0, l);
    }
}

// copy 64x64 bf16 (row-major in global) -> swizzled LDS
__device__ __forceinline__ void copy64bf(u16* dst, const u16* __restrict__ src, int t) {
#pragma unroll
    for (int i = 0; i < 4; i++) {
        int e = t + 256 * i;
        int row = e >> 4, c0 = (e & 15) << 2;
        ushort4 v = *(const ushort4*)(src + row * 64 + c0);
        st4(dst, row, c0, v);
    }
}

// ---------------- f32 64x64 VALU matmul helpers (small kernels) ----------------
__device__ __forceinline__ void loadT64(float* dst, const float* __restrict__ src, int t) {
    for (int e = t; e < 1024; e += 256) {
        int m = e >> 4, k0 = (e & 15) << 2;
        float4 v = *(const float4*)(src + m * 64 + k0);
        dst[(k0 + 0) * 64 + m] = v.x;
        dst[(k0 + 1) * 64 + m] = v.y;
        dst[(k0 + 2) * 64 + m] = v.z;
        dst[(k0 + 3) * 64 + m] = v.w;
    }
}
__device__ __forceinline__ void mm64add(const float* Acm, const float* Brm,
                                        float acc[4][4], int i0, int j0) {
#pragma unroll 8
    for (int k = 0; k < 64; k++) {
        float4 a = *(const float4*)(Acm + k * 64 + i0);
        float4 b = *(const float4*)(Brm + k * 64 + j0);
        acc[0][0] += a.x * b.x; acc[0][1] += a.x * b.y; acc[0][2] += a.x * b.z; acc[0][3] += a.x * b.w;
        acc[1][0] += a.y * b.x; acc[1][1] += a.y * b.y; acc[1][2] += a.y * b.z; acc[1][3] += a.y * b.w;
        acc[2][0] += a.z * b.x; acc[2][1] += a.z * b.y; acc[2][2] += a.z * b.z; acc[2][3] += a.z * b.w;
        acc[3][0] += a.w * b.x; acc[3][1] += a.w * b.y; acc[3][2] += a.w * b.z; acc[3][3] += a.w * b.w;
    }
}
__device__ __forceinline__ void mm64(const float* Acm, const float* Brm,
                                     float acc[4][4], int i0, int j0) {
#pragma unroll
    for (int r = 0; r < 4; r++)
#pragma unroll
        for (int c = 0; c < 4; c++) acc[r][c] = 0.f;
    mm64add(Acm, Brm, acc, i0, j0);
}
__device__ __forceinline__ void writeN64(float* dst, const float acc[4][4], int i0, int j0, float s) {
#pragma unroll
    for (int r = 0; r < 4; r++) {
        float4 v;
        v.x = s * acc[r][0]; v.y = s * acc[r][1]; v.z = s * acc[r][2]; v.w = s * acc[r][3];
        *(float4*)(dst + (i0 + r) * 64 + j0) = v;
    }
}

// ---------- kernel A: row sums of Q and K ----------
__global__ __launch_bounds__(256) void k_sums(const float* __restrict__ Qg,
                                              const float* __restrict__ Kg, float* ws) {
    size_t row = (size_t)blockIdx.x * 64 + (threadIdx.x >> 2);
    int q = threadIdx.x & 3;
    const float4* qp = (const float4*)(Qg + row * 64 + q * 16);
    const float4* kp = (const float4*)(Kg + row * 64 + q * 16);
    float s1 = 0.f, s2 = 0.f;
#pragma unroll
    for (int i = 0; i < 4; i++) { float4 v = qp[i]; s1 += (v.x + v.y) + (v.z + v.w); }
#pragma unroll
    for (int i = 0; i < 4; i++) { float4 v = kp[i]; s2 += (v.x + v.y) + (v.z + v.w); }
    s1 += __shfl_xor(s1, 1); s1 += __shfl_xor(s1, 2);
    s2 += __shfl_xor(s2, 1); s2 += __shfl_xor(s2, 2);
    if (q == 0) { ws[OFF_SUMQ + row] = s1; ws[OFF_SUMK + row] = s2; }
}

// ---------- kernel B: top-64 select via MSB radix-select + gather ----------
__global__ __launch_bounds__(256) void k_select(const float* __restrict__ Qg,
                                                const float* __restrict__ Kg, float* ws) {
    int head = blockIdx.x, sel = blockIdx.y, t = threadIdx.x;
    __shared__ int hist[257];
    __shared__ int idx_s[64];
    __shared__ unsigned s_prefix;
    __shared__ int s_need, s_cnt, s_win;
    __shared__ int wred[4];
    const float* scores = ws + (sel ? OFF_SUMQ : OFF_SUMK) + (size_t)head * 4096;
    unsigned uu[16];
#pragma unroll
    for (int i = 0; i < 16; i++) {
        unsigned u = __float_as_uint(scores[t + 256 * i]);
        uu[i] = (u & 0x80000000u) ? ~u : (u | 0x80000000u);
    }
    if (t == 0) { s_prefix = 0u; s_need = 64; }
    __syncthreads();
#pragma unroll
    for (int p = 0; p < 4; p++) {
        hist[t] = 0;
        if (t == 0) hist[256] = 0;
        __syncthreads();
        unsigned pref = s_prefix;
        int sh = 32 - 8 * p;
        int dsh = 24 - 8 * p;
#pragma unroll
        for (int i = 0; i < 16; i++) {
            bool active = (p == 0) || ((uu[i] >> sh) == (pref >> sh));
            if (active) atomicAdd(&hist[(uu[i] >> dsh) & 255], 1);
        }
        __syncthreads();
        for (int s = 1; s < 256; s <<= 1) {
            int v = (t + s < 256) ? hist[t + s] : 0;
            __syncthreads();
            hist[t] += v;
            __syncthreads();
        }
        int need = s_need;
        __syncthreads();
        if (hist[t] >= need && (t == 255 || hist[t + 1] < need)) {
            s_need = need - ((t == 255) ? 0 : hist[t + 1]);
            s_prefix = pref | ((unsigned)t << dsh);
        }
        __syncthreads();
    }
    unsigned thr = s_prefix;
    int needEq = s_need;
    if (t == 0) s_cnt = 0;
    __syncthreads();
    unsigned eqm = 0;
#pragma unroll
    for (int i = 0; i < 16; i++) {
        if (uu[i] > thr) { int pos = atomicAdd(&s_cnt, 1); idx_s[pos] = t + 256 * i; }
        else if (uu[i] == thr) eqm |= (1u << i);
    }
    __syncthreads();
    int base = 64 - needEq;
    int lane = t & 63, wid = t >> 6;
    for (int r = 0; r < needEq; r++) {
        int mymin = 0x7FFFFFFF;
#pragma unroll
        for (int i = 0; i < 16; i++)
            if ((eqm >> i) & 1) mymin = min(mymin, t + 256 * i);
#pragma unroll
        for (int s = 1; s < 64; s <<= 1) mymin = min(mymin, __shfl_xor(mymin, s));
        if (lane == 0) wred[wid] = mymin;
        __syncthreads();
        if (t == 0) {
            int wv = min(min(wred[0], wred[1]), min(wred[2], wred[3]));
            s_win = wv;
            idx_s[base + r] = wv;
        }
        __syncthreads();
        int wv = s_win;
        if ((wv & 255) == t) eqm &= ~(1u << (wv >> 8));
        __syncthreads();
    }
    // gather selected rows
    const float* src = sel ? Qg : Kg;
    float* dst = ws + (sel ? OFF_NR : OFF_NC) + (size_t)head * 4096;
    u16* dh = (u16*)(ws + OFF_NCH) + (size_t)head * 4096;
    u16* dl = (u16*)(ws + OFF_NCL) + (size_t)head * 4096;
    float scl = sel ? 0.125f : 1.0f;
    for (int e = t; e < 4096; e += 256) {
        int m = e >> 6, d = e & 63;
        float v = src[((size_t)head * NSEQ + (size_t)idx_s[m]) * 64 + d] * scl;
        dst[e] = v;
        if (!sel) { u16 h, l; splitbf(v, h, l); dh[e] = h; dl[e] = l; }
    }
}

// ---------- kernel C: u = softmax(nr @ nc^T) + per-head max colsum ----------
__global__ __launch_bounds__(256) void k_u(float* ws) {
    int head = blockIdx.x, t = threadIdx.x;
    __shared__ __align__(16) float A_s[4096];
    __shared__ __align__(16) float B_s[4096];
    __shared__ float colpart[1024];
    loadT64(A_s, ws + OFF_NR + (size_t)head * 4096, t);
    loadT64(B_s, ws + OFF_NC + (size_t)head * 4096, t);
    __syncthreads();
    int ti = t >> 4, tj = t & 15, i0 = ti << 2, j0 = tj << 2;
    float acc[4][4];
    mm64(A_s, B_s, acc, i0, j0);
#pragma unroll
    for (int r = 0; r < 4; r++) {
        float m0 = fmaxf(fmaxf(acc[r][0], acc[r][1]), fmaxf(acc[r][2], acc[r][3]));
        m0 = fmaxf(m0, __shfl_xor(m0, 1)); m0 = fmaxf(m0, __shfl_xor(m0, 2));
        m0 = fmaxf(m0, __shfl_xor(m0, 4)); m0 = fmaxf(m0, __shfl_xor(m0, 8));
        float s = 0.f;
#pragma unroll
        for (int c = 0; c < 4; c++) { acc[r][c] = __expf(acc[r][c] - m0); s += acc[r][c]; }
        s += __shfl_xor(s, 1); s += __shfl_xor(s, 2);
        s += __shfl_xor(s, 4); s += __shfl_xor(s, 8);
#pragma unroll
        for (int c = 0; c < 4; c++) acc[r][c] = acc[r][c] / s;
    }
    float* u = ws + OFF_U + (size_t)head * 4096;
#pragma unroll
    for (int r = 0; r < 4; r++) {
        float4 v; v.x = acc[r][0]; v.y = acc[r][1]; v.z = acc[r][2]; v.w = acc[r][3];
        *(float4*)(u + (i0 + r) * 64 + j0) = v;
    }
#pragma unroll
    for (int c = 0; c < 4; c++)
        colpart[ti * 64 + j0 + c] = acc[0][c] + acc[1][c] + acc[2][c] + acc[3][c];
    __syncthreads();
    if (t < 64) {
        float cs = 0.f;
#pragma unroll
        for (int g = 0; g < 16; g++) cs += colpart[g * 64 + t];
        float v = cs;
#pragma unroll
        for (int s = 1; s < 64; s <<= 1) v = fmaxf(v, __shfl_xor(v, s));
        if (t == 0) ws[OFF_HMAX + head] = v;
    }
}

// ---------- kernel E: Newton-Schulz inverse via MFMA split-bf16 ----------
__global__ __launch_bounds__(256) void k_nsinv(float* ws) {
    int head = blockIdx.x, t = threadIdx.x;
    __shared__ __align__(16) u16 KmH[4096], KmL[4096];
    __shared__ __align__(16) u16 VmNH[4096], VmNL[4096];
    __shared__ __align__(16) u16 VmTH[4096], VmTL[4096];
    __shared__ __align__(16) u16 KVH[4096], KVL[4096];
    __shared__ __align__(16) u16 BtH[4096], BtL[4096];
    __shared__ __align__(16) float Vmf[4096];

    int w = t >> 6, lane = t & 63, lrow = lane & 15, lk = (lane >> 4) << 3;
    int mrow0 = 16 * w + ((lane >> 4) << 2);

    float g = ws[OFF_HMAX + lane];
#pragma unroll
    for (int s = 1; s < 64; s <<= 1) g = fmaxf(g, __shfl_xor(g, s));
    float ginv = 1.0f / g;

    const float* u = ws + OFF_U + (size_t)head * 4096;
#pragma unroll
    for (int i = 0; i < 4; i++) {
        int e = t + 256 * i;
        int row = e >> 4, c0 = (e & 15) << 2;
        float4 v = *(const float4*)(u + row * 64 + c0);
        float vv[4] = {v.x, v.y, v.z, v.w};
        ushort4 h4, l4;
        splitbf(vv[0], h4.x, l4.x); splitbf(vv[1], h4.y, l4.y);
        splitbf(vv[2], h4.z, l4.z); splitbf(vv[3], h4.w, l4.w);
        st4(KmH, row, c0, h4); st4(KmL, row, c0, l4);
        float sv[4] = {vv[0] * ginv, vv[1] * ginv, vv[2] * ginv, vv[3] * ginv};
        splitbf(sv[0], h4.x, l4.x); splitbf(sv[1], h4.y, l4.y);
        splitbf(sv[2], h4.z, l4.z); splitbf(sv[3], h4.w, l4.w);
        st4(VmTH, row, c0, h4); st4(VmTL, row, c0, l4);
#pragma unroll
        for (int k = 0; k < 4; k++) {
            u16 h, l; splitbf(sv[k], h, l);
            stb16(VmNH, c0 + k, row, h); stb16(VmNL, c0 + k, row, l);
            Vmf[(c0 + k) * 64 + row] = sv[k];
        }
    }
    __syncthreads();

    f32x4 cv[4];
    for (int it = 0; it < 6; it++) {
        {
            short8 a0h = ldfrag(KmH, 16 * w + lrow, lk);
            short8 a0l = ldfrag(KmL, 16 * w + lrow, lk);
            short8 a1h = ldfrag(KmH, 16 * w + lrow, 32 + lk);
            short8 a1l = ldfrag(KmL, 16 * w + lrow, 32 + lk);
#pragma unroll
            for (int nt = 0; nt < 4; nt++) {
                f32x4 acc = (f32x4){0.f, 0.f, 0.f, 0.f};
                short8 bh = ldfrag(VmTH, 16 * nt + lrow, lk);
                short8 bl = ldfrag(VmTL, 16 * nt + lrow, lk);
                acc = MFMA(a0h, bh, acc); acc = MFMA(a0l, bh, acc); acc = MFMA(a0h, bl, acc);
                bh = ldfrag(VmTH, 16 * nt + lrow, 32 + lk);
                bl = ldfrag(VmTL, 16 * nt + lrow, 32 + lk);
                acc = MFMA(a1h, bh, acc); acc = MFMA(a1l, bh, acc); acc = MFMA(a1h, bl, acc);
                cv[nt] = acc;
            }
        }
#pragma unroll
        for (int nt = 0; nt < 4; nt++)
#pragma unroll
            for (int j = 0; j < 4; j++) {
                int m = mrow0 + j, n = 16 * nt + lrow;
                float v = cv[nt][j];
                u16 h, l; splitbf(v, h, l);
                stb16(KVH, m, n, h); stb16(KVL, m, n, l);
                float b = ((m == n) ? 7.f : 0.f) - v;
                splitbf(b, h, l);
                stb16(BtH, n, m, h); stb16(BtL, n, m, l);
            }
        __syncthreads();
        {
            short8 a0h = ldfrag(KVH, 16 * w + lrow, lk);
            short8 a0l = ldfrag(KVL, 16 * w + lrow, lk);
            short8 a1h = ldfrag(KVH, 16 * w + lrow, 32 + lk);
            short8 a1l = ldfrag(KVL, 16 * w + lrow, 32 + lk);
#pragma unroll
            for (int nt = 0; nt < 4; nt++) {
                f32x4 acc = (f32x4){0.f, 0.f, 0.f, 0.f};
                short8 bh = ldfrag(BtH, 16 * nt + lrow, lk);
                short8 bl = ldfrag(BtL, 16 * nt + lrow, lk);
                acc = MFMA(a0h, bh, acc); acc = MFMA(a0l, bh, acc); acc = MFMA(a0h, bl, acc);
                bh = ldfrag(BtH, 16 * nt + lrow, 32 + lk);
                bl = ldfrag(BtL, 16 * nt + lrow, 32 + lk);
                acc = MFMA(a1h, bh, acc); acc = MFMA(a1l, bh, acc); acc = MFMA(a1h, bl, acc);
                cv[nt] = acc;
            }
        }
        __syncthreads();
#pragma unroll
        for (int nt = 0; nt < 4; nt++)
#pragma unroll
            for (int j = 0; j < 4; j++) {
                int m = mrow0 + j, n = 16 * nt + lrow;
                float b = ((m == n) ? 15.f : 0.f) - cv[nt][j];
                u16 h, l; splitbf(b, h, l);
                stb16(BtH, n, m, h); stb16(BtL, n, m, l);
            }
        __syncthreads();
        {
            short8 a0h = ldfrag(KVH, 16 * w + lrow, lk);
            short8 a0l = ldfrag(KVL, 16 * w + lrow, lk);
            short8 a1h = ldfrag(KVH, 16 * w + lrow, 32 + lk);
            short8 a1l = ldfrag(KVL, 16 * w + lrow, 32 + lk);
#pragma unroll
            for (int nt = 0; nt < 4; nt++) {
                f32x4 acc = (f32x4){0.f, 0.f, 0.f, 0.f};
                short8 bh = ldfrag(BtH, 16 * nt + lrow, lk);
                short8 bl = ldfrag(BtL, 16 * nt + lrow, lk);
                acc = MFMA(a0h, bh, acc); acc = MFMA(a0l, bh, acc); acc = MFMA(a0h, bl, acc);
                bh = ldfrag(BtH, 16 * nt + lrow, 32 + lk);
                bl = ldfrag(BtL, 16 * nt + lrow, 32 + lk);
                acc = MFMA(a1h, bh, acc); acc = MFMA(a1l, bh, acc); acc = MFMA(a1h, bl, acc);
                cv[nt] = acc;
            }
        }
        __syncthreads();
#pragma unroll
        for (int nt = 0; nt < 4; nt++)
#pragma unroll
            for (int j = 0; j < 4; j++) {
                int m = mrow0 + j, n = 16 * nt + lrow;
                float b = ((m == n) ? 13.f : 0.f) - cv[nt][j];
                u16 h, l; splitbf(b, h, l);
                stb16(BtH, n, m, h); stb16(BtL, n, m, l);
            }
        __syncthreads();
        {
            short8 a0h = ldfrag(VmNH, 16 * w + lrow, lk);
            short8 a0l = ldfrag(VmNL, 16 * w + lrow, lk);
            short8 a1h = ldfrag(VmNH, 16 * w + lrow, 32 + lk);
            short8 a1l = ldfrag(VmNL, 16 * w + lrow, 32 + lk);
#pragma unroll
            for (int nt = 0; nt < 4; nt++) {
                f32x4 acc = (f32x4){0.f, 0.f, 0.f, 0.f};
                short8 bh = ldfrag(BtH, 16 * nt + lrow, lk);
                short8 bl = ldfrag(BtL, 16 * nt + lrow, lk);
                acc = MFMA(a0h, bh, acc); acc = MFMA(a0l, bh, acc); acc = MFMA(a0h, bl, acc);
                bh = ldfrag(BtH, 16 * nt + lrow, 32 + lk);
                bl = ldfrag(BtL, 16 * nt + lrow, 32 + lk);
                acc = MFMA(a1h, bh, acc); acc = MFMA(a1l, bh, acc); acc = MFMA(a1h, bl, acc);
                cv[nt] = acc;
            }
        }
        __syncthreads();
#pragma unroll
        for (int nt = 0; nt < 4; nt++)
#pragma unroll
            for (int j = 0; j < 4; j++) {
                int m = mrow0 + j, n = 16 * nt + lrow;
                float v = 0.25f * cv[nt][j];
                u16 h, l; splitbf(v, h, l);
                stb16(VmNH, m, n, h); stb16(VmNL, m, n, l);
                stb16(VmTH, n, m, h); stb16(VmTL, n, m, l);
                Vmf[m * 64 + n] = v;
            }
        __syncthreads();
    }

    float* vm = ws + OFF_VM + (size_t)head * 4096;
#pragma unroll
    for (int i = 0; i < 4; i++) {
        int e = t + 256 * i;
        int row = e >> 4, c0 = (e & 15) << 2;
        *(float4*)(vm + row * 64 + c0) = *(const float4*)(Vmf + row * 64 + c0);
    }
}

// ---------- kernel F: flash softmax(nr@K^T)@V — swapped-QK, in-reg P, prefetch ----------
__global__ __launch_bounds__(256) void k_rvp(const float* __restrict__ Kg,
                                             const float* __restrict__ Vg, float* ws) {
    int head = blockIdx.x, ch = blockIdx.y, t = threadIdx.x;
    const int nsub = (NSEQ / 64) / NCH;       // 8 subtiles of 64 rows per chunk
    __shared__ __align__(16) u16 Kh[4096], Kl[4096];
    __shared__ __align__(16) u16 Vth[4096], Vtl[4096];   // V^T: rows d, cols n
    int w = t >> 6, lane = t & 63, lrow = lane & 15, g = lane >> 4;
    int lk = g << 3;
    int mrow0 = 16 * w + (g << 2);
    // staging coords
    int krow = t >> 4, kc0 = (t & 15) << 2;   // K: rows krow+16i, cols kc0..kc0+3
    int vn0 = (t & 15) << 2, vd0 = (t >> 4) << 2;  // V: 4x4 block (n0..n0+3, d0..d0+3)

    // nr B-fragments direct from global f32
    short8 nh0, nl0, nh1, nl1;
    {
        const float* nr = ws + OFF_NR + (size_t)head * 4096 + (size_t)(16 * w + lrow) * 64;
        float a[8], b[8];
        *(float4*)(a + 0) = *(const float4*)(nr + lk);
        *(float4*)(a + 4) = *(const float4*)(nr + lk + 4);
        *(float4*)(b + 0) = *(const float4*)(nr + 32 + lk);
        *(float4*)(b + 4) = *(const float4*)(nr + 32 + lk + 4);
#pragma unroll
        for (int i = 0; i < 8; i++) {
            u16 h, l;
            splitbf(a[i], h, l); nh0[i] = (short)h; nl0[i] = (short)l;
            splitbf(b[i], h, l); nh1[i] = (short)h; nl1[i] = (short)l;
        }
    }

    f32x4 rv[4];
#pragma unroll
    for (int dt = 0; dt < 4; dt++) rv[dt] = (f32x4){0.f, 0.f, 0.f, 0.f};
    float mrow = -INFINITY, srow = 0.f;       // stats for P-row m = 16w + lrow

    const int rows = NSEQ / NCH;
    const float* Kb = Kg + ((size_t)head * NSEQ + (size_t)ch * rows) * 64;
    const float* Vb = Vg + ((size_t)head * NSEQ + (size_t)ch * rows) * 64;

    // prefetch tile 0 into registers
    float4 kreg[4], vreg[4];
#pragma unroll
    for (int i = 0; i < 4; i++)
        kreg[i] = *(const float4*)(Kb + (krow + 16 * i) * 64 + kc0);
#pragma unroll
    for (int k = 0; k < 4; k++)
        vreg[k] = *(const float4*)(Vb + (vn0 + k) * 64 + vd0);

    for (int s8 = 0; s8 < nsub; s8++) {
        // write staged regs -> LDS
#pragma unroll
        for (int i = 0; i < 4; i++) {
            ushort4 h4, l4;
            splitbf(kreg[i].x, h4.x, l4.x); splitbf(kreg[i].y, h4.y, l4.y);
            splitbf(kreg[i].z, h4.z, l4.z); splitbf(kreg[i].w, h4.w, l4.w);
            st4(Kh, krow + 16 * i, kc0, h4); st4(Kl, krow + 16 * i, kc0, l4);
        }
#pragma unroll
        for (int dd = 0; dd < 4; dd++) {      // 4x4 in-register transpose
            float x0 = ((const float*)&vreg[0])[dd];
            float x1 = ((const float*)&vreg[1])[dd];
            float x2 = ((const float*)&vreg[2])[dd];
            float x3 = ((const float*)&vreg[3])[dd];
            ushort4 h4, l4;
            splitbf(x0, h4.x, l4.x); splitbf(x1, h4.y, l4.y);
            splitbf(x2, h4.z, l4.z); splitbf(x3, h4.w, l4.w);
            unsigned byte = vt_byte(vd0 + dd, vn0);
            *(ushort4*)((char*)Vth + byte) = h4;
            *(ushort4*)((char*)Vtl + byte) = l4;
        }
        __syncthreads();
        // issue next tile's global loads (in flight during compute)
        if (s8 + 1 < nsub) {
            const float* Kn = Kb + (s8 + 1) * 4096;
            const float* Vn = Vb + (s8 + 1) * 4096;
#pragma unroll
            for (int i = 0; i < 4; i++)
                kreg[i] = *(const float4*)(Kn + (krow + 16 * i) * 64 + kc0);
#pragma unroll
            for (int k = 0; k < 4; k++)
                vreg[k] = *(const float4*)(Vn + (vn0 + k) * 64 + vd0);
        }

        // swapped QK^T: cv[nt][j] = S[m = 16w+lrow][n = 16nt + 4g + j]
        f32x4 cv[4];
#pragma unroll
        for (int nt = 0; nt < 4; nt++) {
            f32x4 acc = (f32x4){0.f, 0.f, 0.f, 0.f};
            short8 ah = ldfrag(Kh, 16 * nt + lrow, lk);
            short8 al = ldfrag(Kl, 16 * nt + lrow, lk);
            acc = MFMA(ah, nh0, acc); acc = MFMA(al, nh0, acc); acc = MFMA(ah, nl0, acc);
            ah = ldfrag(Kh, 16 * nt + lrow, 32 + lk);
            al = ldfrag(Kl, 16 * nt + lrow, 32 + lk);
            acc = MFMA(ah, nh1, acc); acc = MFMA(al, nh1, acc); acc = MFMA(ah, nl1, acc);
            cv[nt] = acc;
        }
        // row softmax: reduce 16 regs + lanes ^16, ^32
        float m0 = cv[0][0];
#pragma unroll
        for (int nt = 0; nt < 4; nt++)
#pragma unroll
            for (int j = 0; j < 4; j++) m0 = fmaxf(m0, cv[nt][j]);
        m0 = fmaxf(m0, __shfl_xor(m0, 16));
        m0 = fmaxf(m0, __shfl_xor(m0, 32));
        float mnew = fmaxf(mrow, m0);
        float sc = __expf(mrow - mnew);
        float ps = 0.f;
#pragma unroll
        for (int nt = 0; nt < 4; nt++)
#pragma unroll
            for (int j = 0; j < 4; j++) {
                float p = __expf(cv[nt][j] - mnew);
                cv[nt][j] = p; ps += p;
            }
        ps += __shfl_xor(ps, 16);
        ps += __shfl_xor(ps, 32);
        srow = srow * sc + ps;
        mrow = mnew;
        float scl[4];
#pragma unroll
        for (int j = 0; j < 4; j++) scl[j] = __shfl(sc, (g << 2) + j);
#pragma unroll
        for (int dt = 0; dt < 4; dt++)
#pragma unroll
            for (int j = 0; j < 4; j++) rv[dt][j] *= scl[j];
        // pack P into A-fragments: slot 8g+i <-> n = 32h2 + 16(i>>2) + 4g + (i&3)
        short8 pah[2], pal[2];
#pragma unroll
        for (int h2 = 0; h2 < 2; h2++)
#pragma unroll
            for (int i = 0; i < 8; i++) {
                u16 hh, ll;
                splitbf(cv[2 * h2 + (i >> 2)][i & 3], hh, ll);
                pah[h2][i] = (short)hh; pal[h2][i] = (short)ll;
            }
        // PV: B-frag = V^T[d = 16dt+lrow][slots], two b64 reads per frag
#pragma unroll
        for (int dt = 0; dt < 4; dt++) {
            int drow = 16 * dt + lrow;
#pragma unroll
            for (int h2 = 0; h2 < 2; h2++) {
                bf4 xh0 = *(const bf4*)((const char*)Vth + vt_byte(drow, 32 * h2 + 4 * g));
                bf4 xh1 = *(const bf4*)((const char*)Vth + vt_byte(drow, 32 * h2 + 16 + 4 * g));
                bf4 xl0 = *(const bf4*)((const char*)Vtl + vt_byte(drow, 32 * h2 + 4 * g));
                bf4 xl1 = *(const bf4*)((const char*)Vtl + vt_byte(drow, 32 * h2 + 16 + 4 * g));
                short8 bh = __builtin_shufflevector(xh0, xh1, 0, 1, 2, 3, 4, 5, 6, 7);
                short8 bl = __builtin_shufflevector(xl0, xl1, 0, 1, 2, 3, 4, 5, 6, 7);
                rv[dt] = MFMA(pah[h2], bh, rv[dt]);
                rv[dt] = MFMA(pal[h2], bh, rv[dt]);
                rv[dt] = MFMA(pah[h2], bl, rv[dt]);
            }
        }
        __syncthreads();                      // LDS reads done before next store
    }
    size_t pb = (size_t)(head * NCH + ch) * 64;
    if (lane < 16) {
        ws[OFF_PMAX + pb + 16 * w + lane] = mrow;
        ws[OFF_PSUM + pb + 16 * w + lane] = srow;
    }
#pragma unroll
    for (int dt = 0; dt < 4; dt++)
#pragma unroll
        for (int j = 0; j < 4; j++)
            ws[OFF_PRV + (pb + mrow0 + j) * 64 + 16 * dt + lrow] = rv[dt][j];
}

// ---------- kernel G: combine partials -> RV; W = k2inv @ RV; write W^T bf16 ----------
__global__ __launch_bounds__(256) void k_comb(float* ws) {
    int head = blockIdx.x, t = threadIdx.x;
    const int nch = NCH;
    __shared__ __align__(16) float A_s[4096];
    __shared__ __align__(16) float B_s[4096];
    loadT64(A_s, ws + OFF_VM + (size_t)head * 4096, t);
    int ti = t >> 4, tj = t & 15, i0 = ti << 2, j0 = tj << 2;
    const float* pm = ws + OFF_PMAX + (size_t)head * nch * 64;
    const float* psv = ws + OFF_PSUM + (size_t)head * nch * 64;
    const float* prv = ws + OFF_PRV + (size_t)head * nch * 4096;
    float gm[4] = {-INFINITY, -INFINITY, -INFINITY, -INFINITY};
    for (int c8 = 0; c8 < nch; c8++)
#pragma unroll
        for (int r = 0; r < 4; r++) gm[r] = fmaxf(gm[r], pm[c8 * 64 + i0 + r]);
    float stot[4] = {0.f, 0.f, 0.f, 0.f};
    float racc[4][4];
#pragma unroll
    for (int r = 0; r < 4; r++)
#pragma unroll
        for (int c = 0; c < 4; c++) racc[r][c] = 0.f;
    for (int c8 = 0; c8 < nch; c8++) {
#pragma unroll
        for (int r = 0; r < 4; r++) {
            float w = __expf(pm[c8 * 64 + i0 + r] - gm[r]);
            stot[r] += w * psv[c8 * 64 + i0 + r];
            float4 v = *(const float4*)(prv + (size_t)(c8 * 64 + i0 + r) * 64 + j0);
            racc[r][0] += w * v.x; racc[r][1] += w * v.y;
            racc[r][2] += w * v.z; racc[r][3] += w * v.w;
        }
    }
#pragma unroll
    for (int r = 0; r < 4; r++)
#pragma unroll
        for (int c = 0; c < 4; c++) racc[r][c] /= stot[r];
    writeN64(B_s, racc, i0, j0, 1.f);
    __syncthreads();
    float acc[4][4];
    mm64(A_s, B_s, acc, i0, j0);
    u16* wth = (u16*)(ws + OFF_WTH) + (size_t)head * 4096;
    u16* wtl = (u16*)(ws + OFF_WTL) + (size_t)head * 4096;
#pragma unroll
    for (int r = 0; r < 4; r++)
#pragma unroll
        for (int c = 0; c < 4; c++) {
            u16 h, l; splitbf(acc[r][c], h, l);
            wth[(j0 + c) * 64 + (i0 + r)] = h;   // W^T[d][n]
            wtl[(j0 + c) * 64 + (i0 + r)] = l;
        }
}

// ---------- kernel H: X = softmax(Q@nc^T/8) @ W — MFMA split-bf16 ----------
__global__ __launch_bounds__(256) void k_final(const float* __restrict__ Qg, float* ws,
                                               float* __restrict__ out) {
    int tile = blockIdx.x, head = blockIdx.y, t = threadIdx.x;
    __shared__ __align__(16) u16 Ah[4096], Al[4096];   // Q then P
    __shared__ __align__(16) u16 Bh[4096], Bl[4096];   // nc then W^T
    __shared__ __align__(16) float C[64 * 68];
    const float* Qt = Qg + ((size_t)head * NSEQ + (size_t)tile * 64) * 64;
    stage64(Qt, Ah, Al, t, 0.125f);
    copy64bf(Bh, (const u16*)(ws + OFF_NCH) + (size_t)head * 4096, t);
    copy64bf(Bl, (const u16*)(ws + OFF_NCL) + (size_t)head * 4096, t);
    __syncthreads();
    int w = t >> 6, lane = t & 63, lrow = lane & 15, lk = (lane >> 4) << 3;
    int mrow0 = 16 * w + ((lane >> 4) << 2);
    short8 a0h = ldfrag(Ah, 16 * w + lrow, lk);
    short8 a0l = ldfrag(Al, 16 * w + lrow, lk);
    short8 a1h = ldfrag(Ah, 16 * w + lrow, 32 + lk);
    short8 a1l = ldfrag(Al, 16 * w + lrow, 32 + lk);
    f32x4 sa[4];
#pragma unroll
    for (int nt = 0; nt < 4; nt++) {
        f32x4 acc = (f32x4){0.f, 0.f, 0.f, 0.f};
        short8 bh = ldfrag(Bh, 16 * nt + lrow, lk);
        short8 bl = ldfrag(Bl, 16 * nt + lrow, lk);
        acc = MFMA(a0h, bh, acc); acc = MFMA(a0l, bh, acc); acc = MFMA(a0h, bl, acc);
        bh = ldfrag(Bh, 16 * nt + lrow, 32 + lk);
        bl = ldfrag(Bl, 16 * nt + lrow, 32 + lk);
        acc = MFMA(a1h, bh, acc); acc = MFMA(a1l, bh, acc); acc = MFMA(a1h, bl, acc);
        sa[nt] = acc;
    }
#pragma unroll
    for (int j = 0; j < 4; j++) {
        float m0 = fmaxf(fmaxf(sa[0][j], sa[1][j]), fmaxf(sa[2][j], sa[3][j]));
        m0 = fmaxf(m0, __shfl_xor(m0, 1)); m0 = fmaxf(m0, __shfl_xor(m0, 2));
        m0 = fmaxf(m0, __shfl_xor(m0, 4)); m0 = fmaxf(m0, __shfl_xor(m0, 8));
        float ps = 0.f;
#pragma unroll
        for (int nt = 0; nt < 4; nt++) {
            float p = __expf(sa[nt][j] - m0);
            sa[nt][j] = p; ps += p;
        }
        ps += __shfl_xor(ps, 1); ps += __shfl_xor(ps, 2);
        ps += __shfl_xor(ps, 4); ps += __shfl_xor(ps, 8);
        float inv = 1.f / ps;
#pragma unroll
        for (int nt = 0; nt < 4; nt++) sa[nt][j] *= inv;
    }
    __syncthreads();                           // done reading Q/nc from LDS
#pragma unroll
    for (int nt = 0; nt < 4; nt++)
#pragma unroll
        for (int j = 0; j < 4; j++) {
            u16 h, l; splitbf(sa[nt][j], h, l);
            stb16(Ah, mrow0 + j, 16 * nt + lrow, h);
            stb16(Al, mrow0 + j, 16 * nt + lrow, l);
        }
    copy64bf(Bh, (const u16*)(ws + OFF_WTH) + (size_t)head * 4096, t);
    copy64bf(Bl, (const u16*)(ws + OFF_WTL) + (size_t)head * 4096, t);
    __syncthreads();
    short8 p0h = ldfrag(Ah, 16 * w + lrow, lk);
    short8 p0l = ldfrag(Al, 16 * w + lrow, lk);
    short8 p1h = ldfrag(Ah, 16 * w + lrow, 32 + lk);
    short8 p1l = ldfrag(Al, 16 * w + lrow, 32 + lk);
#pragma unroll
    for (int dt = 0; dt < 4; dt++) {
        f32x4 x = (f32x4){0.f, 0.f, 0.f, 0.f};
        short8 bh = ldfrag(Bh, 16 * dt + lrow, lk);
        short8 bl = ldfrag(Bl, 16 * dt + lrow, lk);
        x = MFMA(p0h, bh, x); x = MFMA(p0l, bh, x); x = MFMA(p0h, bl, x);
        bh = ldfrag(Bh, 16 * dt + lrow, 32 + lk);
        bl = ldfrag(Bl, 16 * dt + lrow, 32 + lk);
        x = MFMA(p1h, bh, x); x = MFMA(p1l, bh, x); x = MFMA(p1h, bl, x);
#pragma unroll
        for (int j = 0; j < 4; j++) C[(mrow0 + j) * 68 + 16 * dt + lrow] = x[j];
    }
    __syncthreads();
    float* op = out + ((size_t)head * NSEQ + (size_t)tile * 64) * 64;
#pragma unroll
    for (int i = 0; i < 4; i++) {
        int e = t + 256 * i;
        int row = e >> 4, c0 = (e & 15) << 2;
        *(float4*)(op + row * 64 + c0) = *(const float4*)(C + row * 68 + c0);
    }
}

// ---------- launcher ----------
extern "C" void kernel_launch(void* const* d_in, const int* in_sizes, int n_in,
                              void* d_out, int out_size, void* d_ws, size_t ws_size,
                              hipStream_t stream) {
    const float* Q = (const float*)d_in[0];
    const float* K = (const float*)d_in[1];
    const float* V = (const float*)d_in[2];
    float* ws = (float*)d_ws;
    float* out = (float*)d_out;

    k_sums<<<4096, 256, 0, stream>>>(Q, K, ws);
    k_select<<<dim3(64, 2), 256, 0, stream>>>(Q, K, ws);
    k_u<<<64, 256, 0, stream>>>(ws);
    k_rvp<<<dim3(64, NCH), 256, 0, stream>>>(K, V, ws);
    k_nsinv<<<64, 256, 0, stream>>>(ws);
    k_comb<<<64, 256, 0, stream>>>(ws);
    k_final<<<dim3(64, 64), 256, 0, stream>>>(Q, ws, out);
}